// Round 2
// baseline (184.101 us; speedup 1.0000x reference)
//
#include <hip/hip_runtime.h>
#include <hip/hip_bf16.h>
#include <cmath>

#define HW 262144          // 512*512
#define NC 16
#define NB 8
#define NSEG 16
#define SEGSZ (HW / NSEG)  // 16384
#define EPS 1e-5f

// ---------------- pass 1: per-(b,c,seg) partial sum & max ----------------
__global__ __launch_bounds__(256) void k_reduce(const float* __restrict__ x,
                                                float* __restrict__ psum,
                                                float* __restrict__ pmax) {
    int plane = blockIdx.x / NSEG;
    int seg   = blockIdx.x - plane * NSEG;
    const float4* p = reinterpret_cast<const float4*>(
        x + (size_t)plane * HW + (size_t)seg * SEGSZ);
    int t = threadIdx.x;
    float s = 0.0f, m = -INFINITY;
    #pragma unroll
    for (int it = 0; it < SEGSZ / (256 * 4); ++it) {
        float4 v = p[it * 256 + t];
        s += (v.x + v.y) + (v.z + v.w);
        m = fmaxf(m, fmaxf(fmaxf(v.x, v.y), fmaxf(v.z, v.w)));
    }
    #pragma unroll
    for (int off = 32; off > 0; off >>= 1) {
        s += __shfl_down(s, off, 64);
        m = fmaxf(m, __shfl_down(m, off, 64));
    }
    __shared__ float ls[4], lm[4];
    int wid = t >> 6, lane = t & 63;
    if (lane == 0) { ls[wid] = s; lm[wid] = m; }
    __syncthreads();
    if (t == 0) {
        psum[blockIdx.x] = (ls[0] + ls[1]) + (ls[2] + ls[3]);
        pmax[blockIdx.x] = fmaxf(fmaxf(lm[0], lm[1]), fmaxf(lm[2], lm[3]));
    }
}

// ---------------- pass 2: fold per-batch matrices ----------------
// params layout per batch (816 floats):
// [0:256)   A_T   (A[o][i] stored at i*16+o)
// [256:272) abias
// [272:528) G_T
// [528:544) gbias
// [544:800) W4_T  (W4[o][i] stored at i*16+o)
// [800:816) b4
__global__ __launch_bounds__(256) void k_params(
    const float* __restrict__ psum, const float* __restrict__ pmax,
    const float* __restrict__ Wc, const float* __restrict__ bc,
    const float* __restrict__ W1, const float* __restrict__ b1,
    const float* __restrict__ W2, const float* __restrict__ b2,
    const float* __restrict__ W3, const float* __restrict__ b3,
    const float* __restrict__ W4, const float* __restrict__ b4,
    float* __restrict__ params) {
    int b = blockIdx.x;
    int t = threadIdx.x;
    __shared__ float r2[NC], r4[NC], sWc[256], sW1[256], sW2[256], sW3[256];
    if (t < NC) {
        float s = 0.0f, m = -INFINITY;
        for (int k = 0; k < NSEG; ++k) {
            s += psum[(b * NC + t) * NSEG + k];
            m = fmaxf(m, pmax[(b * NC + t) * NSEG + k]);
        }
        r2[t] = 1.0f / (s * (1.0f / (float)HW) + EPS);
        r4[t] = 1.0f / (m + EPS);
    }
    sWc[t] = Wc[t]; sW1[t] = W1[t]; sW2[t] = W2[t]; sW3[t] = W3[t];
    __syncthreads();
    int o = t >> 4, i = t & 15;
    float accA = 0.0f, accG = 0.0f;
    #pragma unroll
    for (int c = 0; c < NC; ++c) {
        accA += sW2[o * NC + c] * r2[c] * sWc[c * NC + i];
        accG += sW3[o * NC + c] * r4[c] * sW1[c * NC + i];
    }
    float* P = params + b * 816;
    P[i * NC + o]       = accA;
    P[272 + i * NC + o] = accG;
    P[544 + i * NC + o] = W4[o * NC + i];
    if (i == 0) {
        float ba = 0.0f, bg = 0.0f;
        #pragma unroll
        for (int c = 0; c < NC; ++c) {
            ba += sW2[o * NC + c] * r2[c] * bc[c];
            bg += sW3[o * NC + c] * r4[c] * b1[c];
        }
        P[256 + o] = ba + b2[o];
        P[528 + o] = bg + b3[o];
        P[800 + o] = b4[o];
    }
}

// sigmoid(tanh(x)): tanh via fast exp+rcp (saturates correctly at +-inf),
// sigmoid via odd Taylor on [-1,1] (max abs err ~2e-4)
__device__ __forceinline__ float gsig(float x) {
    float E = __expf(2.0f * x);
    float t = 1.0f - 2.0f * __builtin_amdgcn_rcpf(E + 1.0f);   // tanh(x)
    float t2 = t * t;
    return fmaf(t, fmaf(t2, fmaf(t2, 0.0020833333f, -0.0208333333f), 0.25f), 0.5f);
}

#define SIG_P 0.7310586f   // sigmoid(+1)
#define SIG_N 0.2689414f   // sigmoid(-1)

// ---------------- pass 3: fused per-pixel, o-major single pass ----------------
__global__ __launch_bounds__(256, 4) void k_main(const float* __restrict__ x,
                                                 const float* __restrict__ params,
                                                 float* __restrict__ out) {
    int b = blockIdx.x >> 9;            // 512 blocks per batch
    int j = blockIdx.x & 511;
    int p = j * 512 + threadIdx.x * 2;  // 2 pixels per thread
    const float* __restrict__ P = params + b * 816;   // block-uniform -> s_load
    const float* xb = x + (size_t)b * NC * HW + p;
    float* ob = out + (size_t)b * NC * HW + p;

    float2 v[NC];
    #pragma unroll
    for (int c = 0; c < NC; ++c)
        v[c] = *reinterpret_cast<const float2*>(xb + (size_t)c * HW);

    float2 acc[NC];
    #pragma unroll
    for (int q = 0; q < NC; ++q) {
        float bb = P[800 + q];
        acc[q] = make_float2(bb, bb);
    }

    #pragma unroll
    for (int o = 0; o < NC; ++o) {
        float ab = P[256 + o], gb = P[528 + o];
        float whx = ab, why = ab, grx = gb, gry = gb;
        #pragma unroll
        for (int i = 0; i < NC; ++i) {
            float a = P[i * NC + o];
            float g = P[272 + i * NC + o];
            whx = fmaf(a, v[i].x, whx); why = fmaf(a, v[i].y, why);
            grx = fmaf(g, v[i].x, grx); gry = fmaf(g, v[i].y, gry);
        }
        // wh path: A-matrix entries are ~1/mean-amplified (|A|~500), so wh is
        // saturated (|wh|>4 -> sigmoid(tanh(wh)) = sigmoid(+-1) to 1.3e-4)
        // for >99.8% of values. Wave-uniform fast path.
        float s1x, s1y;
        if (__all((fabsf(whx) > 4.0f) && (fabsf(why) > 4.0f))) {
            s1x = whx > 0.0f ? SIG_P : SIG_N;
            s1y = why > 0.0f ? SIG_P : SIG_N;
        } else {
            s1x = gsig(whx); s1y = gsig(why);
        }
        // gr path: gray ~ N(0,~0.2), never saturated -> full gsig
        float s2x = gsig(grx), s2y = gsig(gry);
        // u = v * (1 + s1 + s2)
        float ux = fmaf(v[o].x, s1x + s2x, v[o].x);
        float uy = fmaf(v[o].y, s1y + s2y, v[o].y);
        // scatter into output accumulators: acc[q] += W4[q][o] * u
        #pragma unroll
        for (int q = 0; q < NC; ++q) {
            float wv = P[544 + o * NC + q];   // W4[q][o] stored at [i=o][q]
            acc[q].x = fmaf(wv, ux, acc[q].x);
            acc[q].y = fmaf(wv, uy, acc[q].y);
        }
    }

    #pragma unroll
    for (int q = 0; q < NC; ++q)
        *reinterpret_cast<float2*>(ob + (size_t)q * HW) = acc[q];
}

extern "C" void kernel_launch(void* const* d_in, const int* in_sizes, int n_in,
                              void* d_out, int out_size, void* d_ws, size_t ws_size,
                              hipStream_t stream) {
    const float* x  = (const float*)d_in[0];
    const float* Wc = (const float*)d_in[1];
    const float* bc = (const float*)d_in[2];
    const float* W1 = (const float*)d_in[3];
    const float* b1 = (const float*)d_in[4];
    const float* W2 = (const float*)d_in[5];
    const float* b2 = (const float*)d_in[6];
    const float* W3 = (const float*)d_in[7];
    const float* b3 = (const float*)d_in[8];
    const float* W4 = (const float*)d_in[9];
    const float* b4 = (const float*)d_in[10];
    float* out = (float*)d_out;

    float* psum   = (float*)d_ws;                 // 128*16 floats
    float* pmax   = psum + NB * NC * NSEG;        // 128*16 floats
    float* params = pmax + NB * NC * NSEG;        // 8*816 floats

    k_reduce<<<NB * NC * NSEG, 256, 0, stream>>>(x, psum, pmax);
    k_params<<<NB, 256, 0, stream>>>(psum, pmax, Wc, bc, W1, b1, W2, b2,
                                     W3, b3, W4, b4, params);
    k_main<<<NB * 512, 256, 0, stream>>>(x, params, out);
}

// Round 3
// 115.384 us; speedup vs baseline: 1.5955x; 1.5955x over previous
//
#include <hip/hip_runtime.h>
#include <hip/hip_bf16.h>
#include <cmath>

#define HW 262144          // 512*512
#define NC 16
#define NB 8
#define NSEG 16
#define SEGSZ (HW / NSEG)  // 16384
#define EPS 1e-5f

typedef float f32x2 __attribute__((ext_vector_type(2)));

static __device__ __forceinline__ f32x2 splat2(float s) {
    f32x2 r; r.x = s; r.y = s; return r;
}

// ---------------- pass 1: per-(b,c,seg) partial sum & max ----------------
__global__ __launch_bounds__(256) void k_reduce(const float* __restrict__ x,
                                                float* __restrict__ psum,
                                                float* __restrict__ pmax) {
    int plane = blockIdx.x / NSEG;
    int seg   = blockIdx.x - plane * NSEG;
    const float4* p = reinterpret_cast<const float4*>(
        x + (size_t)plane * HW + (size_t)seg * SEGSZ);
    int t = threadIdx.x;
    float s = 0.0f, m = -INFINITY;
    #pragma unroll
    for (int it = 0; it < SEGSZ / (256 * 4); ++it) {
        float4 v = p[it * 256 + t];
        s += (v.x + v.y) + (v.z + v.w);
        m = fmaxf(m, fmaxf(fmaxf(v.x, v.y), fmaxf(v.z, v.w)));
    }
    #pragma unroll
    for (int off = 32; off > 0; off >>= 1) {
        s += __shfl_down(s, off, 64);
        m = fmaxf(m, __shfl_down(m, off, 64));
    }
    __shared__ float ls[4], lm[4];
    int wid = t >> 6, lane = t & 63;
    if (lane == 0) { ls[wid] = s; lm[wid] = m; }
    __syncthreads();
    if (t == 0) {
        psum[blockIdx.x] = (ls[0] + ls[1]) + (ls[2] + ls[3]);
        pmax[blockIdx.x] = fmaxf(fmaxf(lm[0], lm[1]), fmaxf(lm[2], lm[3]));
    }
}

// ---------------- pass 2: fold per-batch matrices ----------------
// params layout per batch (816 floats):
// [0:256)   A_T   (A[o][i] stored at i*16+o)
// [256:272) abias
// [272:528) G_T
// [528:544) gbias
// [544:800) W4_T  (W4[q][i] stored at i*16+q)
// [800:816) b4
__global__ __launch_bounds__(256) void k_params(
    const float* __restrict__ psum, const float* __restrict__ pmax,
    const float* __restrict__ Wc, const float* __restrict__ bc,
    const float* __restrict__ W1, const float* __restrict__ b1,
    const float* __restrict__ W2, const float* __restrict__ b2,
    const float* __restrict__ W3, const float* __restrict__ b3,
    const float* __restrict__ W4, const float* __restrict__ b4,
    float* __restrict__ params) {
    int b = blockIdx.x;
    int t = threadIdx.x;
    __shared__ float r2[NC], r4[NC], sWc[256], sW1[256], sW2[256], sW3[256];
    if (t < NC) {
        float s = 0.0f, m = -INFINITY;
        for (int k = 0; k < NSEG; ++k) {
            s += psum[(b * NC + t) * NSEG + k];
            m = fmaxf(m, pmax[(b * NC + t) * NSEG + k]);
        }
        r2[t] = 1.0f / (s * (1.0f / (float)HW) + EPS);
        r4[t] = 1.0f / (m + EPS);
    }
    sWc[t] = Wc[t]; sW1[t] = W1[t]; sW2[t] = W2[t]; sW3[t] = W3[t];
    __syncthreads();
    int o = t >> 4, i = t & 15;
    float accA = 0.0f, accG = 0.0f;
    #pragma unroll
    for (int c = 0; c < NC; ++c) {
        accA += sW2[o * NC + c] * r2[c] * sWc[c * NC + i];
        accG += sW3[o * NC + c] * r4[c] * sW1[c * NC + i];
    }
    float* P = params + b * 816;
    P[i * NC + o]       = accA;
    P[272 + i * NC + o] = accG;
    P[544 + i * NC + o] = W4[o * NC + i];
    if (i == 0) {
        float ba = 0.0f, bg = 0.0f;
        #pragma unroll
        for (int c = 0; c < NC; ++c) {
            ba += sW2[o * NC + c] * r2[c] * bc[c];
            bg += sW3[o * NC + c] * r4[c] * b1[c];
        }
        P[256 + o] = ba + b2[o];
        P[528 + o] = bg + b3[o];
        P[800 + o] = b4[o];
    }
}

// sigmoid(tanh(x)) on a packed pair: tanh via fast exp+rcp (saturates
// correctly), sigmoid via odd Taylor on [-1,1] (max abs err ~2e-4).
// Polynomial part runs as v_pk_* ops; exp/rcp are scalar-per-component.
static __device__ __forceinline__ f32x2 gsig2(f32x2 x) {
    f32x2 E;
    E.x = __expf(2.0f * x.x);
    E.y = __expf(2.0f * x.y);
    f32x2 r;
    r.x = __builtin_amdgcn_rcpf(E.x + 1.0f);
    r.y = __builtin_amdgcn_rcpf(E.y + 1.0f);
    f32x2 t = __builtin_elementwise_fma(splat2(-2.0f), r, splat2(1.0f));  // tanh
    f32x2 t2 = t * t;
    f32x2 p = __builtin_elementwise_fma(t2, splat2(0.0020833333f), splat2(-0.0208333333f));
    p = __builtin_elementwise_fma(t2, p, splat2(0.25f));
    return __builtin_elementwise_fma(t, p, splat2(0.5f));
}

// ---------------- pass 3: fused per-pixel, o-split halves, pk-fma ----------------
__global__ __launch_bounds__(256, 4) void k_main(const float* __restrict__ x,
                                                 const float* __restrict__ params,
                                                 float* __restrict__ out) {
    int b = blockIdx.x >> 9;            // 512 blocks per batch
    int j = blockIdx.x & 511;
    int p = j * 512 + threadIdx.x * 2;  // 2 pixels per thread
    const float* __restrict__ P = params + b * 816;   // block-uniform -> s_load
    const float* xb = x + (size_t)b * NC * HW + p;
    float* ob = out + (size_t)b * NC * HW + p;

    f32x2 v[NC];
    #pragma unroll
    for (int c = 0; c < NC; ++c)
        v[c] = *reinterpret_cast<const f32x2*>(xb + (size_t)c * HW);

    f32x2 acc[NC];
    #pragma unroll
    for (int q = 0; q < NC; ++q)
        acc[q] = splat2(P[800 + q]);

    // two halves of 8 output channels: live set = v(32) + acc(32) + wh/gr(32)
    #pragma unroll
    for (int oh = 0; oh < 2; ++oh) {
        f32x2 wh[8], gr[8];
        #pragma unroll
        for (int oo = 0; oo < 8; ++oo) {
            int o = oh * 8 + oo;
            wh[oo] = splat2(P[256 + o]);
            gr[oo] = splat2(P[528 + o]);
        }
        #pragma unroll
        for (int i = 0; i < NC; ++i) {
            f32x2 vi = v[i];
            #pragma unroll
            for (int oo = 0; oo < 8; ++oo) {
                int o = oh * 8 + oo;
                wh[oo] = __builtin_elementwise_fma(vi, splat2(P[i * NC + o]), wh[oo]);
                gr[oo] = __builtin_elementwise_fma(vi, splat2(P[272 + i * NC + o]), gr[oo]);
            }
        }
        #pragma unroll
        for (int oo = 0; oo < 8; ++oo) {
            int o = oh * 8 + oo;
            f32x2 s = gsig2(wh[oo]) + gsig2(gr[oo]);
            f32x2 u = __builtin_elementwise_fma(v[o], s, v[o]);   // v*(1+s1+s2)
            #pragma unroll
            for (int q = 0; q < NC; ++q)
                acc[q] = __builtin_elementwise_fma(u, splat2(P[544 + o * NC + q]), acc[q]);
        }
    }

    #pragma unroll
    for (int q = 0; q < NC; ++q)
        *reinterpret_cast<f32x2*>(ob + (size_t)q * HW) = acc[q];
}

extern "C" void kernel_launch(void* const* d_in, const int* in_sizes, int n_in,
                              void* d_out, int out_size, void* d_ws, size_t ws_size,
                              hipStream_t stream) {
    const float* x  = (const float*)d_in[0];
    const float* Wc = (const float*)d_in[1];
    const float* bc = (const float*)d_in[2];
    const float* W1 = (const float*)d_in[3];
    const float* b1 = (const float*)d_in[4];
    const float* W2 = (const float*)d_in[5];
    const float* b2 = (const float*)d_in[6];
    const float* W3 = (const float*)d_in[7];
    const float* b3 = (const float*)d_in[8];
    const float* W4 = (const float*)d_in[9];
    const float* b4 = (const float*)d_in[10];
    float* out = (float*)d_out;

    float* psum   = (float*)d_ws;                 // 128*16 floats
    float* pmax   = psum + NB * NC * NSEG;        // 128*16 floats
    float* params = pmax + NB * NC * NSEG;        // 8*816 floats

    k_reduce<<<NB * NC * NSEG, 256, 0, stream>>>(x, psum, pmax);
    k_params<<<NB, 256, 0, stream>>>(psum, pmax, Wc, bc, W1, b1, W2, b2,
                                     W3, b3, W4, b4, params);
    k_main<<<NB * 512, 256, 0, stream>>>(x, params, out);
}